// Round 3
// baseline (12788.344 us; speedup 1.0000x reference)
//
#include <hip/hip_runtime.h>
#include <hip/hip_fp16.h>

typedef unsigned int u32;
typedef _Float16 half2_t __attribute__((ext_vector_type(2)));

static constexpr int PL = 300;
static constexpr int QL = 50;
static constexpr int B  = 32;
static constexpr int D  = 256;
static constexpr int H  = 256;

__device__ __forceinline__ float fdot2(u32 w, u32 x, float acc) {
    return __builtin_amdgcn_fdot2(__builtin_bit_cast(half2_t, w),
                                  __builtin_bit_cast(half2_t, x), acc, false);
}
__device__ __forceinline__ u32 packh2(float a, float b) {
    half2_t h2; h2[0] = (_Float16)a; h2[1] = (_Float16)b;
    return __builtin_bit_cast(u32, h2);
}

// ---------------- pack Wr [2][256][256] f32 -> chunk8-packed f16 ----------------
// dst uint index: ((g*32 + kc)*256 + j)*4 + w  ; covers source cols k = kc*8+2w, +1
__global__ __launch_bounds__(256) void pack256(const float* __restrict__ W,
                                               u32* __restrict__ dst) {
    int id = blockIdx.x * 256 + threadIdx.x;      // < 65536
    int g  = id >> 15;
    int r  = id & 32767;
    int kc = r >> 10;
    int j  = (r >> 2) & 255;
    int w  = r & 3;
    int k  = kc * 8 + w * 2;
    const float* s = &W[(g * 256 + j) * 256 + k];
    dst[id] = packh2(s[0], s[1]);
}

// ---------------- pack Wc = [W_ih | W_hh] rows of K=768 ----------------
// dst uint index: ((g*96 + kc)*1024 + j)*4 + w
__global__ __launch_bounds__(256) void packWc(const float* __restrict__ Wih,
                                              const float* __restrict__ Whh,
                                              u32* __restrict__ dst) {
    int id = blockIdx.x * 256 + threadIdx.x;      // < 786432
    int g  = id / 393216;
    int r  = id % 393216;
    int kc = r >> 12;
    int j  = (r >> 2) & 1023;
    int w  = r & 3;
    int k  = kc * 8 + w * 2;
    float a, bb;
    if (k < 512) { const float* s = &Wih[(g * 1024 + j) * 512 + k];         a = s[0]; bb = s[1]; }
    else         { const float* s = &Whh[(g * 1024 + j) * 256 + (k - 512)]; a = s[0]; bb = s[1]; }
    dst[id] = packh2(a, bb);
}

// ---------------- prep: out[g][b][t][h] = bias[g][h] + sum_d X[t][b][d]*W[g][h][d] ----------------
__global__ __launch_bounds__(256) void prep_proj(const float* __restrict__ X,
                                                 const float* __restrict__ W,
                                                 const float* __restrict__ Bv,
                                                 __half* __restrict__ out,
                                                 int T, int nt) {
    int id = blockIdx.x;
    int tb = id % nt; id /= nt;
    int b  = id % B;  id /= B;
    int g  = id;
    int t0 = tb * 8;
    int nr = T - t0; if (nr > 8) nr = 8;
    __shared__ __align__(16) float xs[8][256];
    int tid = threadIdx.x;
    for (int r = 0; r < nr; r++) xs[r][tid] = X[((t0 + r) * B + b) * D + tid];
    __syncthreads();
    const float4* wrow = (const float4*)&W[(g * H + tid) * D];
    float bb = Bv[g * H + tid];
    float acc[8];
#pragma unroll
    for (int r = 0; r < 8; r++) acc[r] = bb;
    for (int d4 = 0; d4 < D / 4; d4++) {
        float4 w = wrow[d4];
#pragma unroll
        for (int r = 0; r < 8; r++) {
            float4 x = *(const float4*)&xs[r][d4 * 4];
            acc[r] = fmaf(w.x, x.x, fmaf(w.y, x.y, fmaf(w.z, x.z, fmaf(w.w, x.w, acc[r]))));
        }
    }
    for (int r = 0; r < nr; r++)
        out[((g * B + b) * T + t0 + r) * H + tid] = __float2half(acc[r]);
}

// ---------------- main scan: 4 blocks per (dir,batch) chain, weights in registers ----------------
// block = 256 threads (4 waves). Block k0 of chain (g,b) owns gate rows
// {kind*256 + 64*k0 + j : kind<4, j<64}. grid=256 <= #CUs and 1 block/CU by
// VGPR limit -> all blocks co-resident; spin-wait is safe without coop launch.
// Exchange is double-buffered by step parity (prevents overwrite race).
__global__ __launch_bounds__(256, 1) void scan2(
    const float* __restrict__ cv,      // [300][32][256]
    const int*   __restrict__ cmask,   // [32][300]
    const float* __restrict__ qv,      // [50][32][256]
    const int*   __restrict__ qmask,   // [32][50]
    const float* __restrict__ Wgv,     // [2][256]
    const float* __restrict__ bgv,     // [2]
    const float* __restrict__ lngp,    // [2][512]
    const float* __restrict__ lnbp,    // [2][512]
    const float* __restrict__ brp,     // [2][256]
    const float* __restrict__ bih,     // [2][1024]
    const float* __restrict__ bhh,     // [2][1024]
    const u32*   __restrict__ Wr4,     // packed f16 Wr
    const u32*   __restrict__ Wc4,     // packed f16 [Wih|Whh]
    const __half* __restrict__ whp,    // [2][32][50][256]
    const __half* __restrict__ hpp,    // [2][32][300][256]
    float*       __restrict__ exch_h,   // [2][64][4][64]   (parity-double-buffered)
    float*       __restrict__ exch_hrp, // [2][64][4][256]
    u32*         __restrict__ flags,    // [64][4][16] (64B padded)
    float* __restrict__ out)           // [300][32][512]
{
    int blk = blockIdx.x;              // 0..255
    int k0  = blk >> 6;                // which quarter of the chain
    int cid = blk & 63;                // chain id  (all 4 parts: blk ≡ cid mod 8 -> same XCD)
    int g = cid >> 5, b = cid & 31;
    int tid  = threadIdx.x;            // 0..255
    int lane = tid & 63, wave = tid >> 6;

    __shared__ __align__(16) u32  sh_wh[6400];    // wh f16 [50][256]
    __shared__ __align__(16) u32  sh_W2[8192];    // Wr col-slice pairs [32][256]
    __shared__ __align__(16) u32  sh_x[384];      // x = [z_norm(512) | h(256)] f16 pairs
    __shared__ float sh_g[256];
    __shared__ float sh_hr[256];                  // hr + br + hp
    __shared__ u32   sh_hm2[32];                  // own h slice, f16 pairs
    __shared__ u32   sh_al2[32];                  // alpha f16 pairs
    __shared__ float sh_alpha[64];
    __shared__ float sh_red[16];
    __shared__ float sh_qb[64];
    __shared__ int   sh_len;

    // ---- persistent registers ----
    uint4 wreg[96];                    // my gate row (768 f16) of Wc
    u32   qvreg[25];                   // qv[:, tid] as f16 q-pairs
    int row = wave * 256 + k0 * 64 + (tid & 63);   // NOTE: wave = kind here

    {
        const uint4* wcq = (const uint4*)Wc4 + (size_t)g * 96 * 1024;
#pragma unroll
        for (int kc = 0; kc < 96; kc++) wreg[kc] = wcq[kc * 1024 + row];
    }
#pragma unroll
    for (int q2 = 0; q2 < 25; q2++) {
        float a  = qv[(2 * q2) * (B * D) + b * D + tid];
        float bb = qv[(2 * q2 + 1) * (B * D) + b * D + tid];
        qvreg[q2] = packh2(a, bb);
    }
    // stage wh
    {
        const u32* whsrc = (const u32*)(whp + (size_t)(g * B + b) * QL * H);
        for (int i = tid; i < 6400; i += 256) sh_wh[i] = whsrc[i];
    }
    // stage Wr column-slice: sh_W2[j2*256+l] = (Wr[l][64k0+2j2], Wr[l][64k0+2j2+1])
#pragma unroll
    for (int j2 = 0; j2 < 32; j2++) {
        int kc = 8 * k0 + (j2 >> 2), w = j2 & 3;
        sh_W2[j2 * 256 + tid] = Wr4[((size_t)(g * 32 + kc) * 256 + tid) * 4 + w];
    }
    if (tid < 64) sh_qb[tid] = (tid < QL) ? (qmask[b * QL + tid] ? 0.f : -1e30f) : -1e30f;

    // hoisted constants
    float wgr[4];
#pragma unroll
    for (int i = 0; i < 4; i++) wgr[i] = Wgv[g * H + (tid & 63) + i * 64];
    float bgs   = bgv[g];
    float bias_g = bih[g * 1024 + row] + bhh[g * 1024 + row];
    float lng0 = lngp[g * 512 + tid], lng1 = lngp[g * 512 + 256 + tid];
    float lnb0 = lnbp[g * 512 + tid], lnb1 = lnbp[g * 512 + 256 + tid];
    float brv  = brp[g * H + tid];

    // length
    if (wave == 0) {
        int s = 0;
        for (int t = lane; t < PL; t += 64) s += cmask[b * PL + t];
#pragma unroll
        for (int m = 32; m; m >>= 1) s += __shfl_xor(s, m, 64);
        if (lane == 0) sh_len = s;
    }
    if (tid < 32) sh_hm2[tid] = 0;
    __syncthreads();
    int len = sh_len;

    // zero my 64-column slice of the masked output tail
    for (int i = tid; i < (PL - len) * 64; i += 256) {
        int t = len + (i >> 6), j = i & 63;
        out[(t * B + b) * 512 + g * 256 + k0 * 64 + j] = 0.f;
    }

    u32* my_flag = &flags[(cid * 4 + k0) * 16];

    // initial exchange: data_0 (h = 0) into parity-0 buffer
    {
        float* eh0  = exch_h   + ((0 * 64 + cid) * 4 + k0) * 64;
        float* ehr0 = exch_hrp + ((0 * 64 + cid) * 4 + k0) * 256;
        if (tid < 64) eh0[tid] = 0.f;
        ehr0[tid] = 0.f;
    }
    __threadfence();
    __syncthreads();
    if (tid == 0)
        __hip_atomic_store(my_flag, 1u, __ATOMIC_RELEASE, __HIP_MEMORY_SCOPE_AGENT);

    float c_reg = 0.f;
    const __half* hpb = hpp + (size_t)(g * B + b) * PL * H;

    for (int t = 0; t < len; t++) {
        int t_src = g ? (len - 1 - t) : t;

        // prefetch (independent of exchange)
        float cvv = cv[(t_src * B + b) * D + tid];
        float hpv = (float)hpb[(size_t)t_src * H + tid];

        // ---- poll: all 4 slices of data_t published ----
        if (wave == 0 && lane < 4 && lane != k0) {
            const u32* fl = &flags[(cid * 4 + lane) * 16];
            while (__hip_atomic_load(fl, __ATOMIC_ACQUIRE, __HIP_MEMORY_SCOPE_AGENT)
                   < (u32)(t + 1))
                __builtin_amdgcn_s_sleep(1);
        }
        __syncthreads();
        __threadfence();   // acquire: invalidate stale cached exch lines

        // gather hr = sum of partials + br + hp ; full h for x   (read parity t&1)
        {
            const float* eh  = exch_h   + ((t & 1) * 64 + cid) * 4 * 64;
            const float* ehr = exch_hrp + ((t & 1) * 64 + cid) * 4 * 256;
            float hrs = ehr[tid] + ehr[256 + tid] + ehr[512 + tid] + ehr[768 + tid];
            sh_hr[tid] = hrs + brv + hpv;
            float hval = eh[tid];            // [4][64] layout == flat [256]
            float ho = __shfl_xor(hval, 1, 64);
            if (!(tid & 1)) sh_x[256 + (tid >> 1)] = packh2(hval, ho);
        }
        __syncthreads();

        // ---- attention logits (replicated): wave-strided q ----
        {
            float hrv[4];
#pragma unroll
            for (int i = 0; i < 4; i++) hrv[i] = sh_hr[(tid & 63) + 64 * i];
            const __half* wh16 = (const __half*)sh_wh;
            for (int q = wave; q < QL; q += 4) {
                float a = 0.f;
#pragma unroll
                for (int i = 0; i < 4; i++) {
                    float x = (float)wh16[q * H + (tid & 63) + 64 * i] + hrv[i];
                    float e = __expf(2.f * x);
                    float th = (e - 1.f) / (e + 1.f);
                    a = fmaf(wgr[i], th, a);
                }
#pragma unroll
                for (int m = 32; m; m >>= 1) a += __shfl_xor(a, m, 64);
                if (lane == 0) sh_alpha[q] = a + bgs + sh_qb[q];
            }
        }
        __syncthreads();

        // ---- softmax over 50 (wave 0), pack alpha to f16 pairs ----
        if (wave == 0) {
            float v = (lane < QL) ? sh_alpha[lane] : -1e30f;
            float m = v;
#pragma unroll
            for (int s = 32; s; s >>= 1) m = fmaxf(m, __shfl_xor(m, s, 64));
            float e = (lane < QL) ? __expf(v - m) : 0.f;
            float sum = e;
#pragma unroll
            for (int s = 32; s; s >>= 1) sum += __shfl_xor(sum, s, 64);
            float al = e / sum;
            float alo = __shfl_xor(al, 1, 64);
            if (lane < QL && !(lane & 1)) sh_al2[lane >> 1] = packh2(al, alo);
        }
        __syncthreads();

        // ---- h_alpha + layernorm + pack z ----
        {
            float ha0 = 0.f, ha1 = 0.f;
#pragma unroll
            for (int q2 = 0; q2 < 25; q2 += 2) ha0 = fdot2(qvreg[q2], sh_al2[q2], ha0);
#pragma unroll
            for (int q2 = 1; q2 < 25; q2 += 2) ha1 = fdot2(qvreg[q2], sh_al2[q2], ha1);
            float z0 = cvv, z1 = ha0 + ha1;
            float sx = z0 + z1, sxx = z0 * z0 + z1 * z1;
#pragma unroll
            for (int s = 32; s; s >>= 1) {
                sx  += __shfl_xor(sx, s, 64);
                sxx += __shfl_xor(sxx, s, 64);
            }
            if (lane == 0) { sh_red[wave] = sx; sh_red[8 + wave] = sxx; }
            __syncthreads();
            float s  = sh_red[0] + sh_red[1] + sh_red[2] + sh_red[3];
            float ss = sh_red[8] + sh_red[9] + sh_red[10] + sh_red[11];
            float mu = s * (1.f / 512.f);
            float rs = rsqrtf(ss * (1.f / 512.f) - mu * mu + 1e-5f);
            float z0n = (z0 - mu) * rs * lng0 + lnb0;
            float z1n = (z1 - mu) * rs * lng1 + lnb1;
            float o0 = __shfl_xor(z0n, 1, 64);
            float o1 = __shfl_xor(z1n, 1, 64);
            int m2 = tid >> 1;
            if (!(tid & 1)) sh_x[m2] = packh2(z0n, o0);
            else            sh_x[128 + m2] = packh2(o1, z1n);
        }
        __syncthreads();

        // ---- gates: my row dot x (weights in registers, x broadcast from LDS) ----
        {
            float a0 = bias_g, a1 = 0.f, a2 = 0.f, a3 = 0.f;
#pragma unroll
            for (int kc = 0; kc < 96; kc += 4) {
                uint4 x0 = *(const uint4*)&sh_x[(kc + 0) * 4];
                uint4 w0 = wreg[kc + 0];
                a0 = fdot2(w0.x, x0.x, a0); a0 = fdot2(w0.y, x0.y, a0);
                a0 = fdot2(w0.z, x0.z, a0); a0 = fdot2(w0.w, x0.w, a0);
                uint4 x1 = *(const uint4*)&sh_x[(kc + 1) * 4];
                uint4 w1 = wreg[kc + 1];
                a1 = fdot2(w1.x, x1.x, a1); a1 = fdot2(w1.y, x1.y, a1);
                a1 = fdot2(w1.z, x1.z, a1); a1 = fdot2(w1.w, x1.w, a1);
                uint4 x2 = *(const uint4*)&sh_x[(kc + 2) * 4];
                uint4 w2 = wreg[kc + 2];
                a2 = fdot2(w2.x, x2.x, a2); a2 = fdot2(w2.y, x2.y, a2);
                a2 = fdot2(w2.z, x2.z, a2); a2 = fdot2(w2.w, x2.w, a2);
                uint4 x3 = *(const uint4*)&sh_x[(kc + 3) * 4];
                uint4 w3 = wreg[kc + 3];
                a3 = fdot2(w3.x, x3.x, a3); a3 = fdot2(w3.y, x3.y, a3);
                a3 = fdot2(w3.z, x3.z, a3); a3 = fdot2(w3.w, x3.w, a3);
            }
            sh_g[tid] = (a0 + a1) + (a2 + a3);
        }
        __syncthreads();

        // ---- LSTM pointwise for my 64 h (wave 0); write h into parity (t+1)&1 ----
        float* eh_w  = exch_h   + (((t + 1) & 1) * 64 + cid) * 4 * 64  + k0 * 64;
        float* ehr_w = exch_hrp + (((t + 1) & 1) * 64 + cid) * 4 * 256 + k0 * 256;
        if (tid < 64) {
            float iv = sh_g[tid], fv = sh_g[64 + tid], gv = sh_g[128 + tid], ov = sh_g[192 + tid];
            float si = 1.f / (1.f + __expf(-iv));
            float sf = 1.f / (1.f + __expf(-fv));
            float so = 1.f / (1.f + __expf(-ov));
            float eg = __expf(2.f * gv); float tg = (eg - 1.f) / (eg + 1.f);
            float c = sf * c_reg + si * tg;
            float ec = __expf(2.f * c); float tc = (ec - 1.f) / (ec + 1.f);
            float hv = so * tc;
            c_reg = c;
            out[(t_src * B + b) * 512 + g * 256 + k0 * 64 + tid] = hv;
            eh_w[tid] = hv;
            float ho = __shfl_xor(hv, 1, 64);
            if (!(tid & 1)) sh_hm2[tid >> 1] = packh2(hv, ho);
        }
        __syncthreads();

        // ---- hr partial from my h slice -> parity (t+1)&1 ----
        {
            float p0 = 0.f, p1 = 0.f;
#pragma unroll
            for (int j2 = 0; j2 < 32; j2 += 2) p0 = fdot2(sh_W2[j2 * 256 + tid], sh_hm2[j2], p0);
#pragma unroll
            for (int j2 = 1; j2 < 32; j2 += 2) p1 = fdot2(sh_W2[j2 * 256 + tid], sh_hm2[j2], p1);
            ehr_w[tid] = p0 + p1;
        }
        __threadfence();   // release: my stores visible before flag
        __syncthreads();
        if (tid == 0)
            __hip_atomic_store(my_flag, (u32)(t + 2),
                               __ATOMIC_RELEASE, __HIP_MEMORY_SCOPE_AGENT);
    }
}

extern "C" void kernel_launch(void* const* d_in, const int* in_sizes, int n_in,
                              void* d_out, int out_size, void* d_ws, size_t ws_size,
                              hipStream_t stream) {
    const float* cv    = (const float*)d_in[0];
    const int*   cmask = (const int*)  d_in[1];
    const float* qv    = (const float*)d_in[2];
    const int*   qmask = (const int*)  d_in[3];
    const float* Wq    = (const float*)d_in[4];
    const float* bq    = (const float*)d_in[5];
    const float* Wp    = (const float*)d_in[6];
    const float* bp    = (const float*)d_in[7];
    const float* Wr    = (const float*)d_in[8];
    const float* br    = (const float*)d_in[9];
    const float* Wg    = (const float*)d_in[10];
    const float* bg    = (const float*)d_in[11];
    const float* ln_g  = (const float*)d_in[12];
    const float* ln_b  = (const float*)d_in[13];
    const float* Wih   = (const float*)d_in[14];
    const float* Whh   = (const float*)d_in[15];
    const float* b_ih  = (const float*)d_in[16];
    const float* b_hh  = (const float*)d_in[17];
    float* out = (float*)d_out;

    uint8_t* ws = (uint8_t*)d_ws;
    u32*    Wr4 = (u32*)ws;    ws += (size_t)2 * 32 * 256 * 4 * 4;    // 256 KB
    u32*    Wc4 = (u32*)ws;    ws += (size_t)2 * 96 * 1024 * 4 * 4;   // 3 MB
    __half* whp = (__half*)ws; ws += (size_t)2 * 32 * 50 * 256 * 2;   // 1.6 MB
    __half* hpp = (__half*)ws; ws += (size_t)2 * 32 * 300 * 256 * 2;  // 9.8 MB
    float* exch_h   = (float*)ws; ws += (size_t)2 * 64 * 4 * 64 * 4;  // 128 KB
    float* exch_hrp = (float*)ws; ws += (size_t)2 * 64 * 4 * 256 * 4; // 512 KB
    u32*   flags    = (u32*)ws;                                       // 16 KB

    hipMemsetAsync(flags, 0, (size_t)64 * 4 * 16 * 4, stream);
    hipLaunchKernelGGL(pack256, dim3(256), dim3(256), 0, stream, Wr, Wr4);
    hipLaunchKernelGGL(packWc, dim3(3072), dim3(256), 0, stream, Wih, Whh, Wc4);
    hipLaunchKernelGGL(prep_proj, dim3(2 * 32 * 7), dim3(256), 0, stream,
                       qv, Wq, bq, whp, QL, 7);
    hipLaunchKernelGGL(prep_proj, dim3(2 * 32 * 38), dim3(256), 0, stream,
                       cv, Wp, bp, hpp, PL, 38);
    hipLaunchKernelGGL(scan2, dim3(256), dim3(256), 0, stream,
                       cv, cmask, qv, qmask, Wg, bg, ln_g, ln_b, br, b_ih, b_hh,
                       Wr4, Wc4, whp, hpp, exch_h, exch_hrp, flags, out);
}

// Round 4
// 12635.519 us; speedup vs baseline: 1.0121x; 1.0121x over previous
//
#include <hip/hip_runtime.h>
#include <hip/hip_fp16.h>

typedef unsigned int u32;
typedef _Float16 half2_t __attribute__((ext_vector_type(2)));
typedef _Float16 f16x8 __attribute__((ext_vector_type(8)));
typedef float f32x16 __attribute__((ext_vector_type(16)));

static constexpr int PL = 300;
static constexpr int QL = 50;
static constexpr int B  = 32;
static constexpr int D  = 256;
static constexpr int H  = 256;
static constexpr int XPAD = 388;   // uints per sh_x / sh_w row (16B aligned, %32==4)

__device__ __forceinline__ float fdot2(u32 w, u32 x, float acc) {
    return __builtin_amdgcn_fdot2(__builtin_bit_cast(half2_t, w),
                                  __builtin_bit_cast(half2_t, x), acc, false);
}
__device__ __forceinline__ u32 packh2(float a, float b) {
    half2_t h2; h2[0] = (_Float16)a; h2[1] = (_Float16)b;
    return __builtin_bit_cast(u32, h2);
}

// ---- pack Wc rows: Wcp[g][1024 r][384 u] = (Wrow[2u], Wrow[2u+1]) f16, Wrow=[Wih|Whh] ----
__global__ __launch_bounds__(256) void pack_wc_rows(const float* __restrict__ Wih,
                                                    const float* __restrict__ Whh,
                                                    u32* __restrict__ dst) {
    int id = blockIdx.x * 256 + threadIdx.x;        // < 786432
    int g = id / 393216;
    int rem = id % 393216;
    int r = rem / 384, u = rem % 384;
    int k = 2 * u;
    float a, b;
    if (k < 512) { const float* s = &Wih[(g * 1024 + r) * 512 + k];         a = s[0]; b = s[1]; }
    else         { const float* s = &Whh[(g * 1024 + r) * 256 + (k - 512)]; a = s[0]; b = s[1]; }
    dst[id] = packh2(a, b);
}

// ---- pack Wr rows: Wrp[g][256 r][128 u] ----
__global__ __launch_bounds__(256) void pack_wr_rows(const float* __restrict__ W,
                                                    u32* __restrict__ dst) {
    int id = blockIdx.x * 256 + threadIdx.x;        // < 65536
    int g = id / 32768;
    int rem = id % 32768;
    int r = rem / 128, u = rem % 128;
    const float* s = &W[(g * 256 + r) * 256 + 2 * u];
    dst[id] = packh2(s[0], s[1]);
}

// ---- prep: out[g][b][t][h] = bias[g][h] + sum_d X[t][b][d]*W[g][h][d] ----
__global__ __launch_bounds__(256) void prep_proj(const float* __restrict__ X,
                                                 const float* __restrict__ W,
                                                 const float* __restrict__ Bv,
                                                 __half* __restrict__ out,
                                                 int T, int nt) {
    int id = blockIdx.x;
    int tb = id % nt; id /= nt;
    int b  = id % B;  id /= B;
    int g  = id;
    int t0 = tb * 8;
    int nr = T - t0; if (nr > 8) nr = 8;
    __shared__ __align__(16) float xs[8][256];
    int tid = threadIdx.x;
    for (int r = 0; r < nr; r++) xs[r][tid] = X[((t0 + r) * B + b) * D + tid];
    __syncthreads();
    const float4* wrow = (const float4*)&W[(g * H + tid) * D];
    float bb = Bv[g * H + tid];
    float acc[8];
#pragma unroll
    for (int r = 0; r < 8; r++) acc[r] = bb;
    for (int d4 = 0; d4 < D / 4; d4++) {
        float4 w = wrow[d4];
#pragma unroll
        for (int r = 0; r < 8; r++) {
            float4 x = *(const float4*)&xs[r][d4 * 4];
            acc[r] = fmaf(w.x, x.x, fmaf(w.y, x.y, fmaf(w.z, x.z, fmaf(w.w, x.w, acc[r]))));
        }
    }
    for (int r = 0; r < nr; r++)
        out[((g * B + b) * T + t0 + r) * H + tid] = __float2half(acc[r]);
}

// ================= main scan: 64 blocks = 2 dirs x 32 slices, lockstep t =================
__global__ __launch_bounds__(256, 1) void scan3(
    const float* __restrict__ cv,       // [300][32][256]
    const int*   __restrict__ cmask,    // [32][300]
    const float* __restrict__ qv,       // [50][32][256]
    const int*   __restrict__ qmask,    // [32][50]
    const float* __restrict__ Wgv,      // [2][256]
    const float* __restrict__ bgv,      // [2]
    const float* __restrict__ lngp,     // [2][512]
    const float* __restrict__ lnbp,     // [2][512]
    const float* __restrict__ brp,      // [2][256]
    const float* __restrict__ bihp,     // [2][1024]
    const float* __restrict__ bhhp,     // [2][1024]
    const u32*   __restrict__ Wcp,      // [2][1024][384]
    const u32*   __restrict__ Wrp,      // [2][256][128]
    const __half* __restrict__ whp,     // [2][32][50][256]
    const __half* __restrict__ hpp,     // [2][32][300][256]
    u32*   __restrict__ exch_h,         // [2 parity][64][128] uints (f16 pairs)
    float* __restrict__ exch_hr,        // [64][256]
    u32*   __restrict__ exch_z,         // [64][256] uints
    u32*   __restrict__ ctrs,           // [3][2][304]
    float* __restrict__ out)            // [300][32][512]
{
    int blk = blockIdx.x;                   // 0..63
    int dd = (blk >> 2) & 1;                // direction
    int jb = ((blk >> 3) << 2) | (blk & 3); // slice / own-batch 0..31
    int tid  = threadIdx.x;
    int lane = tid & 63, wave = tid >> 6;

    __shared__ __align__(16) u32  sh_w[32 * XPAD];   // gate-weight slice rows (f16 pairs)
    __shared__ __align__(16) u32  sh_x[32 * XPAD];   // x = [z(256u) | h(128u)] per batch
    __shared__ __align__(16) u32  sh_wh[6400];       // wh f16 [50][256] (own batch)
    __shared__ __align__(16) u32  sh_wr[8 * 132];    // Wr slice rows
    __shared__ __align__(16) float sh_red[4 * 32 * 33]; // mfma partials [w][b][r]
    __shared__ float sh_a[256];
    __shared__ float sh_alpha[64];
    __shared__ u32   sh_al2[32];
    __shared__ float sh_qb[64];
    __shared__ float sh_r2[16];
    __shared__ int   sh_len[32];

    // ---------- one-time staging ----------
    for (int v = tid; v < 32 * 384; v += 256) {
        int rl = v / 384, u = v % 384;
        int R = (rl >> 3) * 256 + 8 * jb + (rl & 7);  // kind*256 + 8j + ci
        sh_w[rl * XPAD + u] = Wcp[((size_t)dd * 1024 + R) * 384 + u];
    }
    for (int v = tid; v < 8 * 128; v += 256) {
        int r = v / 128, u = v % 128;
        sh_wr[r * 132 + u] = Wrp[((size_t)dd * 256 + 8 * jb + r) * 128 + u];
    }
    {
        const u32* whsrc = (const u32*)(whp + (size_t)(dd * B + jb) * QL * H);
        for (int i = tid; i < 6400; i += 256) sh_wh[i] = whsrc[i];
    }
    if (tid < 64) sh_qb[tid] = (tid < QL) ? (qmask[jb * QL + tid] ? 0.f : -1e30f) : -1e30f;
    if (tid < 32) sh_len[tid] = 0;
    __syncthreads();
    {
        int b = tid & 31, part = tid >> 5;
        int t0 = part * 38, t1 = t0 + 38 > PL ? PL : t0 + 38;
        int s = 0;
        for (int tt = t0; tt < t1; tt++) s += cmask[b * PL + tt];
        atomicAdd(&sh_len[b], s);
    }
    __syncthreads();

    // per-thread constants
    float wgr[4];
#pragma unroll
    for (int i = 0; i < 4; i++) wgr[i] = Wgv[dd * H + lane + 64 * i];
    float bgs  = bgv[dd];
    float brv  = brp[dd * H + tid];
    float lng0 = lngp[dd * 512 + tid], lng1 = lngp[dd * 512 + 256 + tid];
    float lnb0 = lnbp[dd * 512 + tid], lnb1 = lnbp[dd * 512 + 256 + tid];
    float bias4[4];
#pragma unroll
    for (int k = 0; k < 4; k++)
        bias4[k] = bihp[dd * 1024 + k * 256 + 8 * jb + (tid & 7)]
                 + bhhp[dd * 1024 + k * 256 + 8 * jb + (tid & 7)];
    u32 qvreg[25];
#pragma unroll
    for (int q2 = 0; q2 < 25; q2++) {
        float a  = qv[(2 * q2) * (B * D) + jb * D + tid];
        float bb = qv[(2 * q2 + 1) * (B * D) + jb * D + tid];
        qvreg[q2] = packh2(a, bb);
    }
    int len_j = sh_len[jb];
    float c_reg = 0.f;

    // zero my 8-column slice of masked output tails
    for (int idx = tid; idx < 32 * PL; idx += 256) {
        int b = idx / PL, t = idx % PL;
        if (t >= sh_len[b]) {
            float4 z4 = {0.f, 0.f, 0.f, 0.f};
            float* o = &out[((size_t)t * B + b) * 512 + dd * 256 + 8 * jb];
            *(float4*)o = z4; *(float4*)(o + 4) = z4;
        }
    }

    u32* ctr_h  = ctrs + dd * 304;
    u32* ctr_hr = ctrs + 608 + dd * 304;
    u32* ctr_z  = ctrs + 1216 + dd * 304;

    // prologue: publish h_0 = 0 (parity 0)
    if (tid < 128) {
        int b = tid >> 2, m = tid & 3;
        exch_h[((size_t)0 * 64 + dd * 32 + b) * 128 + 4 * jb + m] = 0;
    }
    __threadfence();
    __syncthreads();
    if (tid == 0)
        __hip_atomic_fetch_add(&ctr_h[0], 1u, __ATOMIC_RELEASE, __HIP_MEMORY_SCOPE_AGENT);

    const __half* hpb = hpp + (size_t)(dd * B + jb) * PL * H;

    for (int t = 0; t < PL; t++) {
        int p = t & 1;
        int tsj = dd ? (t < len_j ? len_j - 1 - t : t) : t;
        float cvv = cv[((size_t)tsj * B + jb) * D + tid];
        float hpv = __half2float(hpb[(size_t)tsj * H + tid]);

        // ---- WAIT H(t) ----
        if (tid == 0) {
            while (__hip_atomic_load(&ctr_h[t], __ATOMIC_RELAXED, __HIP_MEMORY_SCOPE_AGENT) < 32u)
                __builtin_amdgcn_s_sleep(1);
        }
        __syncthreads();
        __threadfence();

        // stage h -> sh_x[][256..384)
        {
            const uint4* src = (const uint4*)(exch_h + ((size_t)p * 64 + dd * 32) * 128);
#pragma unroll
            for (int m = 0; m < 4; m++) {
                int f4 = m * 256 + tid;
                int b = f4 >> 5, c4 = f4 & 31;
                *(uint4*)(sh_x + b * XPAD + 256 + c4 * 4) = src[f4];
            }
        }
        __syncthreads();

        // ---- hr partial: thread (b, ci) ----
        {
            int b = tid >> 3, ci = tid & 7;
            const uint4* wr4 = (const uint4*)(sh_wr + ci * 132);
            const uint4* hx4 = (const uint4*)(sh_x + b * XPAD + 256);
            float p0 = 0.f, p1 = 0.f, p2 = 0.f, p3 = 0.f;
#pragma unroll 8
            for (int kk = 0; kk < 32; kk++) {
                uint4 w = wr4[kk]; uint4 xv = hx4[kk];
                p0 = fdot2(w.x, xv.x, p0); p1 = fdot2(w.y, xv.y, p1);
                p2 = fdot2(w.z, xv.z, p2); p3 = fdot2(w.w, xv.w, p3);
            }
            exch_hr[((size_t)dd * 32 + b) * 256 + 8 * jb + ci] = (p0 + p1) + (p2 + p3);
        }
        __threadfence();
        __syncthreads();
        if (tid == 0)
            __hip_atomic_fetch_add(&ctr_hr[t], 1u, __ATOMIC_RELEASE, __HIP_MEMORY_SCOPE_AGENT);

        // ---- WAIT HR(t) ----
        if (tid == 0) {
            while (__hip_atomic_load(&ctr_hr[t], __ATOMIC_RELAXED, __HIP_MEMORY_SCOPE_AGENT) < 32u)
                __builtin_amdgcn_s_sleep(1);
        }
        __syncthreads();
        __threadfence();

        // ---- attention for own batch jb ----
        sh_a[tid] = exch_hr[((size_t)dd * 32 + jb) * 256 + tid] + brv + hpv;
        __syncthreads();
        {
            float av[4];
#pragma unroll
            for (int i = 0; i < 4; i++) av[i] = sh_a[lane + 64 * i];
            const __half* wh16 = (const __half*)sh_wh;
            for (int q = wave; q < QL; q += 4) {
                float a = 0.f;
#pragma unroll
                for (int i = 0; i < 4; i++) {
                    float xx = (float)wh16[q * 256 + lane + 64 * i] + av[i];
                    float e = __expf(2.f * xx);
                    a = fmaf(wgr[i], (e - 1.f) / (e + 1.f), a);
                }
#pragma unroll
                for (int m = 32; m; m >>= 1) a += __shfl_xor(a, m, 64);
                if (lane == 0) sh_alpha[q] = a + bgs + sh_qb[q];
            }
        }
        __syncthreads();
        if (wave == 0) {
            float v = (lane < QL) ? sh_alpha[lane] : -1e30f;
            float m = v;
#pragma unroll
            for (int s = 32; s; s >>= 1) m = fmaxf(m, __shfl_xor(m, s, 64));
            float e = (lane < QL) ? __expf(v - m) : 0.f;
            float sum = e;
#pragma unroll
            for (int s = 32; s; s >>= 1) sum += __shfl_xor(sum, s, 64);
            float al = e / sum;
            float alo = __shfl_xor(al, 1, 64);
            if (lane < QL && !(lane & 1)) sh_al2[lane >> 1] = packh2(al, alo);
        }
        __syncthreads();
        {
            float ha0 = 0.f, ha1 = 0.f;
#pragma unroll
            for (int q2 = 0; q2 < 25; q2 += 2) ha0 = fdot2(qvreg[q2], sh_al2[q2], ha0);
#pragma unroll
            for (int q2 = 1; q2 < 25; q2 += 2) ha1 = fdot2(qvreg[q2], sh_al2[q2], ha1);
            float z0 = cvv, z1 = ha0 + ha1;
            float sx = z0 + z1, sxx = z0 * z0 + z1 * z1;
#pragma unroll
            for (int s = 32; s; s >>= 1) {
                sx += __shfl_xor(sx, s, 64); sxx += __shfl_xor(sxx, s, 64);
            }
            if (lane == 0) { sh_r2[wave] = sx; sh_r2[8 + wave] = sxx; }
            __syncthreads();
            float s  = sh_r2[0] + sh_r2[1] + sh_r2[2] + sh_r2[3];
            float ss = sh_r2[8] + sh_r2[9] + sh_r2[10] + sh_r2[11];
            float mu = s * (1.f / 512.f);
            float rs = rsqrtf(ss * (1.f / 512.f) - mu * mu + 1e-5f);
            float z0n = (z0 - mu) * rs * lng0 + lnb0;
            float z1n = (z1 - mu) * rs * lng1 + lnb1;
            float o0 = __shfl_xor(z0n, 1, 64);
            float o1 = __shfl_xor(z1n, 1, 64);
            u32* zrow = exch_z + ((size_t)dd * 32 + jb) * 256;
            if (!(tid & 1)) zrow[tid >> 1] = packh2(z0n, o0);
            else            zrow[128 + (tid >> 1)] = packh2(o1, z1n);
        }
        __threadfence();
        __syncthreads();
        if (tid == 0)
            __hip_atomic_fetch_add(&ctr_z[t], 1u, __ATOMIC_RELEASE, __HIP_MEMORY_SCOPE_AGENT);

        // ---- WAIT Z(t) ----
        if (tid == 0) {
            while (__hip_atomic_load(&ctr_z[t], __ATOMIC_RELAXED, __HIP_MEMORY_SCOPE_AGENT) < 32u)
                __builtin_amdgcn_s_sleep(1);
        }
        __syncthreads();
        __threadfence();

        // stage z -> sh_x[][0..256)
        {
            const uint4* src = (const uint4*)(exch_z + (size_t)dd * 32 * 256);
#pragma unroll
            for (int m = 0; m < 8; m++) {
                int f4 = m * 256 + tid;
                int b = f4 >> 6, c4 = f4 & 63;
                *(uint4*)(sh_x + b * XPAD + c4 * 4) = src[f4];
            }
        }
        __syncthreads();

        // ---- gates: 32x32x768 f16 MFMA, k split over 4 waves ----
        {
            int rr = lane & 31, kh = lane >> 5;
            const u32* xp = sh_x + rr * XPAD;
            const u32* wp = sh_w + rr * XPAD;
            int base = wave * 96 + 4 * kh;
            f32x16 acc = {};
#pragma unroll
            for (int kk = 0; kk < 12; kk++) {
                uint4 au = *(const uint4*)(xp + base + kk * 8);
                uint4 bu = *(const uint4*)(wp + base + kk * 8);
                acc = __builtin_amdgcn_mfma_f32_32x32x16_f16(
                    __builtin_bit_cast(f16x8, au), __builtin_bit_cast(f16x8, bu), acc, 0, 0, 0);
            }
#pragma unroll
            for (int q = 0; q < 16; q++) {
                int bb = (q & 3) + 8 * (q >> 2) + 4 * kh;
                sh_red[(wave * 32 + bb) * 33 + rr] = acc[q];
            }
        }
        __syncthreads();

        // ---- pointwise LSTM: thread (b, ci) ----
        {
            int b = tid >> 3, ci = tid & 7;
            float gk[4];
#pragma unroll
            for (int kind = 0; kind < 4; kind++) {
                int rl = kind * 8 + ci;
                float s = bias4[kind];
#pragma unroll
                for (int w = 0; w < 4; w++) s += sh_red[(w * 32 + b) * 33 + rl];
                gk[kind] = s;
            }
            float si = 1.f / (1.f + __expf(-gk[0]));
            float sf = 1.f / (1.f + __expf(-gk[1]));
            float so = 1.f / (1.f + __expf(-gk[3]));
            float eg = __expf(2.f * gk[2]); float tg = (eg - 1.f) / (eg + 1.f);
            float c = sf * c_reg + si * tg;
            float ec = __expf(2.f * c); float tc = (ec - 1.f) / (ec + 1.f);
            float hv = so * tc;
            c_reg = c;
            int lenb = sh_len[b];
            int tsb = dd ? (t < lenb ? lenb - 1 - t : t) : t;
            if (t < lenb)
                out[((size_t)tsb * B + b) * 512 + dd * 256 + 8 * jb + ci] = hv;
            float ho = __shfl_xor(hv, 1, 64);
            if (!(ci & 1))
                exch_h[((size_t)(p ^ 1) * 64 + dd * 32 + b) * 128 + 4 * jb + (ci >> 1)] = packh2(hv, ho);
        }
        __threadfence();
        __syncthreads();
        if (tid == 0)
            __hip_atomic_fetch_add(&ctr_h[t + 1], 1u, __ATOMIC_RELEASE, __HIP_MEMORY_SCOPE_AGENT);
    }
}

extern "C" void kernel_launch(void* const* d_in, const int* in_sizes, int n_in,
                              void* d_out, int out_size, void* d_ws, size_t ws_size,
                              hipStream_t stream) {
    const float* cv    = (const float*)d_in[0];
    const int*   cmask = (const int*)  d_in[1];
    const float* qv    = (const float*)d_in[2];
    const int*   qmask = (const int*)  d_in[3];
    const float* Wq    = (const float*)d_in[4];
    const float* bq    = (const float*)d_in[5];
    const float* Wp    = (const float*)d_in[6];
    const float* bp    = (const float*)d_in[7];
    const float* Wr    = (const float*)d_in[8];
    const float* br    = (const float*)d_in[9];
    const float* Wg    = (const float*)d_in[10];
    const float* bg    = (const float*)d_in[11];
    const float* ln_g  = (const float*)d_in[12];
    const float* ln_b  = (const float*)d_in[13];
    const float* Wih   = (const float*)d_in[14];
    const float* Whh   = (const float*)d_in[15];
    const float* b_ih  = (const float*)d_in[16];
    const float* b_hh  = (const float*)d_in[17];
    float* out = (float*)d_out;

    uint8_t* ws = (uint8_t*)d_ws;
    u32*    Wcp = (u32*)ws;      ws += (size_t)2 * 1024 * 384 * 4;     // 3.0 MB
    u32*    Wrp = (u32*)ws;      ws += (size_t)2 * 256 * 128 * 4;      // 256 KB
    __half* whp = (__half*)ws;   ws += (size_t)2 * 32 * 50 * 256 * 2;  // 1.6 MB
    __half* hpp = (__half*)ws;   ws += (size_t)2 * 32 * 300 * 256 * 2; // 9.8 MB
    u32*   exch_h  = (u32*)ws;   ws += (size_t)2 * 64 * 128 * 4;       // 64 KB
    float* exch_hr = (float*)ws; ws += (size_t)64 * 256 * 4;           // 64 KB
    u32*   exch_z  = (u32*)ws;   ws += (size_t)64 * 256 * 4;           // 64 KB
    u32*   ctrs    = (u32*)ws;                                         // 8 KB

    hipMemsetAsync(ctrs, 0, 2048 * 4, stream);
    hipLaunchKernelGGL(pack_wc_rows, dim3(3072), dim3(256), 0, stream, Wih, Whh, Wcp);
    hipLaunchKernelGGL(pack_wr_rows, dim3(256), dim3(256), 0, stream, Wr, Wrp);
    hipLaunchKernelGGL(prep_proj, dim3(2 * 32 * 7), dim3(256), 0, stream,
                       qv, Wq, bq, whp, QL, 7);
    hipLaunchKernelGGL(prep_proj, dim3(2 * 32 * 38), dim3(256), 0, stream,
                       cv, Wp, bp, hpp, PL, 38);
    hipLaunchKernelGGL(scan3, dim3(64), dim3(256), 0, stream,
                       cv, cmask, qv, qmask, Wg, bg, ln_g, ln_b, br, b_ih, b_hh,
                       Wcp, Wrp, whp, hpp, exch_h, exch_hr, exch_z, ctrs, out);
}

// Round 5
// 5097.354 us; speedup vs baseline: 2.5088x; 2.4788x over previous
//
#include <hip/hip_runtime.h>
#include <hip/hip_fp16.h>

typedef unsigned int u32;
typedef unsigned long long u64;
typedef _Float16 half2_t __attribute__((ext_vector_type(2)));
typedef _Float16 f16x8 __attribute__((ext_vector_type(8)));
typedef float f32x16 __attribute__((ext_vector_type(16)));

static constexpr int PL = 300;
static constexpr int QL = 50;
static constexpr int B  = 32;
static constexpr int D  = 256;
static constexpr int H  = 256;

__device__ __forceinline__ float fdot2(u32 w, u32 x, float acc) {
    return __builtin_amdgcn_fdot2(__builtin_bit_cast(half2_t, w),
                                  __builtin_bit_cast(half2_t, x), acc, false);
}
__device__ __forceinline__ u32 packh2(float a, float b) {
    half2_t h2; h2[0] = (_Float16)a; h2[1] = (_Float16)b;
    return __builtin_bit_cast(u32, h2);
}
__device__ __forceinline__ f32x16 mfma16(uint4 a, uint4 b, f32x16 c) {
    return __builtin_amdgcn_mfma_f32_32x32x16_f16(
        __builtin_bit_cast(f16x8, a), __builtin_bit_cast(f16x8, b), c, 0, 0, 0);
}
__device__ __forceinline__ u32 a_ld32(const u32* p) {
    return __hip_atomic_load(p, __ATOMIC_RELAXED, __HIP_MEMORY_SCOPE_AGENT);
}
__device__ __forceinline__ u64 a_ld64(const u64* p) {
    return __hip_atomic_load(p, __ATOMIC_RELAXED, __HIP_MEMORY_SCOPE_AGENT);
}
__device__ __forceinline__ void a_st32(u32* p, u32 v) {
    __hip_atomic_store(p, v, __ATOMIC_RELAXED, __HIP_MEMORY_SCOPE_AGENT);
}

// ---- pack Wc rows: Wcp[g][1024 r][384 u] = (Wrow[2u], Wrow[2u+1]) f16, Wrow=[Wih|Whh] ----
__global__ __launch_bounds__(256) void pack_wc_rows(const float* __restrict__ Wih,
                                                    const float* __restrict__ Whh,
                                                    u32* __restrict__ dst) {
    int id = blockIdx.x * 256 + threadIdx.x;        // < 786432
    int g = id / 393216;
    int rem = id % 393216;
    int r = rem / 384, u = rem % 384;
    int k = 2 * u;
    float a, b;
    if (k < 512) { const float* s = &Wih[(g * 1024 + r) * 512 + k];         a = s[0]; b = s[1]; }
    else         { const float* s = &Whh[(g * 1024 + r) * 256 + (k - 512)]; a = s[0]; b = s[1]; }
    dst[id] = packh2(a, b);
}

// ---- pack Wr rows: Wrp[g][256 r][128 u] ----
__global__ __launch_bounds__(256) void pack_wr_rows(const float* __restrict__ W,
                                                    u32* __restrict__ dst) {
    int id = blockIdx.x * 256 + threadIdx.x;        // < 65536
    int g = id / 32768;
    int rem = id % 32768;
    int r = rem / 128, u = rem % 128;
    const float* s = &W[(g * 256 + r) * 256 + 2 * u];
    dst[id] = packh2(s[0], s[1]);
}

// ---- prep: out[g][b][t][h] = bias[g][h] + sum_d X[t][b][d]*W[g][h][d] ----
__global__ __launch_bounds__(256) void prep_proj(const float* __restrict__ X,
                                                 const float* __restrict__ W,
                                                 const float* __restrict__ Bv,
                                                 __half* __restrict__ out,
                                                 int T, int nt) {
    int id = blockIdx.x;
    int tb = id % nt; id /= nt;
    int b  = id % B;  id /= B;
    int g  = id;
    int t0 = tb * 8;
    int nr = T - t0; if (nr > 8) nr = 8;
    __shared__ __align__(16) float xs[8][256];
    int tid = threadIdx.x;
    for (int r = 0; r < nr; r++) xs[r][tid] = X[((t0 + r) * B + b) * D + tid];
    __syncthreads();
    const float4* wrow = (const float4*)&W[(g * H + tid) * D];
    float bb = Bv[g * H + tid];
    float acc[8];
#pragma unroll
    for (int r = 0; r < 8; r++) acc[r] = bb;
    for (int d4 = 0; d4 < D / 4; d4++) {
        float4 w = wrow[d4];
#pragma unroll
        for (int r = 0; r < 8; r++) {
            float4 x = *(const float4*)&xs[r][d4 * 4];
            acc[r] = fmaf(w.x, x.x, fmaf(w.y, x.y, fmaf(w.z, x.z, fmaf(w.w, x.w, acc[r]))));
        }
    }
    for (int r = 0; r < nr; r++)
        out[((g * B + b) * T + t0 + r) * H + tid] = __float2half(acc[r]);
}

// ================= main scan: 64 blocks = 2 dirs x 32 slices, lockstep t =================
// Exchange through LLC via relaxed agent-scope atomics (sc0 sc1) — NO fences,
// no L2 writeback/invalidate. Flags = monotonic per-block step counters.
__global__ __launch_bounds__(256, 1) void scan4(
    const float* __restrict__ cv,       // [300][32][256]
    const int*   __restrict__ cmask,    // [32][300]
    const float* __restrict__ qv,       // [50][32][256]
    const int*   __restrict__ qmask,    // [32][50]
    const float* __restrict__ Wgv,      // [2][256]
    const float* __restrict__ bgv,      // [2]
    const float* __restrict__ lngp,     // [2][512]
    const float* __restrict__ lnbp,     // [2][512]
    const float* __restrict__ brp,      // [2][256]
    const float* __restrict__ bihp,     // [2][1024]
    const float* __restrict__ bhhp,     // [2][1024]
    const u32*   __restrict__ Wcp,      // [2][1024][384]
    const u32*   __restrict__ Wrp,      // [2][256][128]
    const __half* __restrict__ whp,     // [2][32][50][256]
    const __half* __restrict__ hpp,     // [2][32][300][256]
    u32* __restrict__ exch_h,           // [2 parity][64][128] u32 (f16 pairs)
    u32* __restrict__ exch_hr,          // [64][256] f32 bits
    u32* __restrict__ exch_z,           // [64][256] u32 (f16 pairs)
    u32* __restrict__ flags,            // [3][2][32*4]
    float* __restrict__ out)            // [300][32][512]
{
    int blk = blockIdx.x;               // 0..63
    int dd = blk >> 5, jb = blk & 31;
    int tid  = threadIdx.x;
    int lane = tid & 63, wave = tid >> 6;

    // LDS: weights rows 0..31 = gate rows (kind*256+8jb+ci), rows 32..39 = Wr rows
    // (h-part cols only); x rows follow so garbage B-rows 40..63 stay in-bounds.
    __shared__ __align__(16) u32 sh_wx[72 * 384];    // 110.6 KB
    u32* sh_w = sh_wx;
    u32* sh_x = sh_wx + 40 * 384;
    __shared__ __align__(16) u32  sh_wh[6400];       // 25.6 KB
    __shared__ float sh_red[4 * 32 * 33];            // 16.9 KB
    __shared__ float sh_a[256];
    __shared__ float sh_alpha[64];
    __shared__ u32   sh_al2[32];
    __shared__ float sh_qb[64];
    __shared__ float sh_r2[16];
    __shared__ int   sh_len[32];

    // ---------- one-time staging (XOR-swizzled: phys c4 = c4 ^ (row&7)) ----------
    for (int v = tid; v < 40 * 384; v += 256) {
        int rl = v / 384, u = v - rl * 384;
        int c4 = u >> 2, w = u & 3;
        u32 val = 0;
        if (rl < 32) {
            int R = (rl >> 3) * 256 + 8 * jb + (rl & 7);
            val = Wcp[((size_t)dd * 1024 + R) * 384 + u];
        } else if (u >= 256) {
            int r = 8 * jb + (rl - 32);
            val = Wrp[((size_t)dd * 256 + r) * 128 + (u - 256)];
        }
        sh_w[rl * 384 + (((c4 ^ (rl & 7)) << 2) | w)] = val;
    }
    for (int v = tid; v < 32 * 384; v += 256) sh_x[v] = 0;
    {
        const u32* whsrc = (const u32*)(whp + (size_t)(dd * B + jb) * QL * H);
        for (int i = tid; i < 6400; i += 256) sh_wh[i] = whsrc[i];
    }
    if (tid < 64) sh_qb[tid] = (tid < QL) ? (qmask[jb * QL + tid] ? 0.f : -1e30f) : -1e30f;
    if (tid < 32) sh_len[tid] = 0;
    __syncthreads();
    {
        int b = tid & 31, part = tid >> 5;
        int t0 = part * 38, t1 = t0 + 38 > PL ? PL : t0 + 38;
        int s = 0;
        for (int tt = t0; tt < t1; tt++) s += cmask[b * PL + tt];
        atomicAdd(&sh_len[b], s);
    }
    __syncthreads();

    // ---------- per-thread constants ----------
    float wgr[4];
#pragma unroll
    for (int i = 0; i < 4; i++) wgr[i] = Wgv[dd * H + lane + 64 * i];
    float bgs  = bgv[dd];
    float brv  = brp[dd * H + tid];
    float lng0 = lngp[dd * 512 + tid], lng1 = lngp[dd * 512 + 256 + tid];
    float lnb0 = lnbp[dd * 512 + tid], lnb1 = lnbp[dd * 512 + 256 + tid];
    float bias4[4];
#pragma unroll
    for (int k = 0; k < 4; k++)
        bias4[k] = bihp[dd * 1024 + k * 256 + 8 * jb + (tid & 7)]
                 + bhhp[dd * 1024 + k * 256 + 8 * jb + (tid & 7)];
    u32 qvreg[25];
#pragma unroll
    for (int q2 = 0; q2 < 25; q2++) {
        float a  = qv[(2 * q2) * (B * D) + jb * D + tid];
        float bb = qv[(2 * q2 + 1) * (B * D) + jb * D + tid];
        qvreg[q2] = packh2(a, bb);
    }
    int len_j = sh_len[jb];
    float c_reg = 0.f;

    // zero my 8-column slice of masked output tails
    for (int idx = tid; idx < 32 * PL; idx += 256) {
        int b = idx / PL, t = idx % PL;
        if (t >= sh_len[b]) {
            float4 z4 = {0.f, 0.f, 0.f, 0.f};
            float* o = &out[((size_t)t * B + b) * 512 + dd * 256 + 8 * jb];
            *(float4*)o = z4; *(float4*)(o + 4) = z4;
        }
    }

    u32* fl_h  = flags + (0 * 2 + dd) * 128;
    u32* fl_hr = flags + (1 * 2 + dd) * 128;
    u32* fl_z  = flags + (2 * 2 + dd) * 128;

    // prologue: publish h(0)=0 into parity 0
    if (tid < 128) {
        int b = tid >> 2, m = tid & 3;
        a_st32(exch_h + ((size_t)(0 * 64 + dd * 32 + b)) * 128 + 4 * jb + m, 0u);
    }
    asm volatile("s_waitcnt vmcnt(0)" ::: "memory");
    __syncthreads();
    if (tid == 0) a_st32(fl_h + jb * 4, 1u);

    const __half* hpb = hpp + (size_t)(dd * B + jb) * PL * H;
    int rr = lane & 31, kh = lane >> 5, sw = rr & 7;
    const u32* xrow  = sh_x + rr * 384;
    const u32* wrow  = sh_w + rr * 384;
    const u32* wrow2 = sh_w + (32 + rr) * 384;   // Wr rows (valid rr<8)

    for (int t = 0; t < PL; t++) {
        int p = t & 1;
        int tsj = dd ? (t < len_j ? len_j - 1 - t : t) : t;
        float cvv = cv[((size_t)tsj * B + jb) * D + tid];
        float hpv = __half2float(hpb[(size_t)tsj * H + tid]);

        // ---- WAIT h(t) ----
        if (wave == 0 && lane < 32) {
            const u32* fp = fl_h + lane * 4;
            while (a_ld32(fp) < (u32)(t + 1)) __builtin_amdgcn_s_sleep(1);
        }
        __syncthreads();

        // stage h -> sh_x[][64..96) uint4 (swizzled)
        {
            const u64* src = (const u64*)(exch_h + (size_t)(p * 64 + dd * 32) * 128);
#pragma unroll
            for (int m = 0; m < 4; m++) {
                int f4 = m * 256 + tid;
                int b = f4 >> 5, c4 = f4 & 31;
                int uoff = b * 128 + c4 * 4;
                u64 lo = a_ld64(src + (uoff >> 1));
                u64 hi = a_ld64(src + (uoff >> 1) + 1);
                u32* dst = sh_x + b * 384 + (((64 + c4) ^ (b & 7)) << 2);
                *(u64*)dst = lo; *(u64*)(dst + 2) = hi;
            }
        }
        __syncthreads();

        // ---- phase 1: MFMA over h-part K: gates-h partial (acc1) + hr rows (acc2) ----
        f32x16 acc1 = {}, acc2 = {};
#pragma unroll
        for (int kk = 0; kk < 4; kk++) {
            int c4 = 64 + wave * 8 + kh + 2 * kk;
            int pc4 = (c4 ^ sw) << 2;
            uint4 au = *(const uint4*)(xrow + pc4);
            uint4 b1 = *(const uint4*)(wrow + pc4);
            uint4 b2 = *(const uint4*)(wrow2 + pc4);
            acc1 = mfma16(au, b1, acc1);
            acc2 = mfma16(au, b2, acc2);
        }
        if (rr < 8) {
#pragma unroll
            for (int q = 0; q < 16; q++) {
                int bb = (q & 3) + 8 * (q >> 2) + 4 * kh;
                sh_red[(wave * 32 + bb) * 33 + rr] = acc2[q];
            }
        }
        __syncthreads();
        {
            int b = tid >> 3, ci = tid & 7;
            float s = sh_red[(0 * 32 + b) * 33 + ci] + sh_red[(1 * 32 + b) * 33 + ci]
                    + sh_red[(2 * 32 + b) * 33 + ci] + sh_red[(3 * 32 + b) * 33 + ci];
            a_st32(exch_hr + (size_t)(dd * 32 + b) * 256 + 8 * jb + ci,
                   __builtin_bit_cast(u32, s));
        }
        asm volatile("s_waitcnt vmcnt(0)" ::: "memory");
        __syncthreads();
        if (tid == 0) a_st32(fl_hr + jb * 4, (u32)(t + 1));

        // ---- WAIT hr(t) ----
        if (wave == 0 && lane < 32) {
            const u32* fp = fl_hr + lane * 4;
            while (a_ld32(fp) < (u32)(t + 1)) __builtin_amdgcn_s_sleep(1);
        }
        __syncthreads();
        sh_a[tid] = __builtin_bit_cast(float,
                        a_ld32(exch_hr + (size_t)(dd * 32 + jb) * 256 + tid))
                    + brv + hpv;
        __syncthreads();

        // ---- attention for own batch jb ----
        {
            float av[4];
#pragma unroll
            for (int i = 0; i < 4; i++) av[i] = sh_a[lane + 64 * i];
            const __half* wh16 = (const __half*)sh_wh;
            for (int q = wave; q < QL; q += 4) {
                float a = 0.f;
#pragma unroll
                for (int i = 0; i < 4; i++) {
                    float xx = (float)wh16[q * 256 + lane + 64 * i] + av[i];
                    float e = __expf(2.f * xx);
                    a = fmaf(wgr[i], (e - 1.f) / (e + 1.f), a);
                }
#pragma unroll
                for (int m = 32; m; m >>= 1) a += __shfl_xor(a, m, 64);
                if (lane == 0) sh_alpha[q] = a + bgs + sh_qb[q];
            }
        }
        __syncthreads();
        if (wave == 0) {
            float v = (lane < QL) ? sh_alpha[lane] : -1e30f;
            float m = v;
#pragma unroll
            for (int s = 32; s; s >>= 1) m = fmaxf(m, __shfl_xor(m, s, 64));
            float e = (lane < QL) ? __expf(v - m) : 0.f;
            float sum = e;
#pragma unroll
            for (int s = 32; s; s >>= 1) sum += __shfl_xor(sum, s, 64);
            float al = e / sum;
            float alo = __shfl_xor(al, 1, 64);
            if (lane < QL && !(lane & 1)) sh_al2[lane >> 1] = packh2(al, alo);
        }
        __syncthreads();
        {
            float ha0 = 0.f, ha1 = 0.f;
#pragma unroll
            for (int q2 = 0; q2 < 25; q2 += 2) ha0 = fdot2(qvreg[q2], sh_al2[q2], ha0);
#pragma unroll
            for (int q2 = 1; q2 < 25; q2 += 2) ha1 = fdot2(qvreg[q2], sh_al2[q2], ha1);
            float z0 = cvv, z1 = ha0 + ha1;
            float sx = z0 + z1, sxx = z0 * z0 + z1 * z1;
#pragma unroll
            for (int s = 32; s; s >>= 1) {
                sx += __shfl_xor(sx, s, 64); sxx += __shfl_xor(sxx, s, 64);
            }
            if (lane == 0) { sh_r2[wave] = sx; sh_r2[8 + wave] = sxx; }
            __syncthreads();
            float s  = sh_r2[0] + sh_r2[1] + sh_r2[2] + sh_r2[3];
            float ss = sh_r2[8] + sh_r2[9] + sh_r2[10] + sh_r2[11];
            float mu = s * (1.f / 512.f);
            float rs = rsqrtf(ss * (1.f / 512.f) - mu * mu + 1e-5f);
            float z0n = (z0 - mu) * rs * lng0 + lnb0;
            float z1n = (z1 - mu) * rs * lng1 + lnb1;
            float o0 = __shfl_xor(z0n, 1, 64);
            float o1 = __shfl_xor(z1n, 1, 64);
            u32* zrow = exch_z + (size_t)(dd * 32 + jb) * 256;
            if (!(tid & 1)) a_st32(zrow + (tid >> 1), packh2(z0n, o0));
            else            a_st32(zrow + 128 + (tid >> 1), packh2(o1, z1n));
        }
        asm volatile("s_waitcnt vmcnt(0)" ::: "memory");
        __syncthreads();
        if (tid == 0) a_st32(fl_z + jb * 4, (u32)(t + 1));

        // ---- WAIT z(t) ----
        if (wave == 0 && lane < 32) {
            const u32* fp = fl_z + lane * 4;
            while (a_ld32(fp) < (u32)(t + 1)) __builtin_amdgcn_s_sleep(1);
        }
        __syncthreads();

        // stage z -> sh_x[][0..64) uint4 (swizzled)
        {
            const u64* src = (const u64*)(exch_z + (size_t)(dd * 32) * 256);
#pragma unroll
            for (int m = 0; m < 8; m++) {
                int f4 = m * 256 + tid;
                int b = f4 >> 6, c4 = f4 & 63;
                int uoff = b * 256 + c4 * 4;
                u64 lo = a_ld64(src + (uoff >> 1));
                u64 hi = a_ld64(src + (uoff >> 1) + 1);
                u32* dst = sh_x + b * 384 + ((c4 ^ (b & 7)) << 2);
                *(u64*)dst = lo; *(u64*)(dst + 2) = hi;
            }
        }
        __syncthreads();

        // ---- phase 2: MFMA over z-part K into acc1; write partials ----
#pragma unroll
        for (int kk = 0; kk < 8; kk++) {
            int c4 = wave * 16 + kh + 2 * kk;
            int pc4 = (c4 ^ sw) << 2;
            uint4 au = *(const uint4*)(xrow + pc4);
            uint4 b1 = *(const uint4*)(wrow + pc4);
            acc1 = mfma16(au, b1, acc1);
        }
#pragma unroll
        for (int q = 0; q < 16; q++) {
            int bb = (q & 3) + 8 * (q >> 2) + 4 * kh;
            sh_red[(wave * 32 + bb) * 33 + rr] = acc1[q];
        }
        __syncthreads();

        // ---- pointwise LSTM: thread (b, ci); publish h(t+1) into parity p^1 ----
        {
            int b = tid >> 3, ci = tid & 7;
            float gk[4];
#pragma unroll
            for (int kind = 0; kind < 4; kind++) {
                int rl = kind * 8 + ci;
                float s = bias4[kind];
#pragma unroll
                for (int w = 0; w < 4; w++) s += sh_red[(w * 32 + b) * 33 + rl];
                gk[kind] = s;
            }
            float si = 1.f / (1.f + __expf(-gk[0]));
            float sf = 1.f / (1.f + __expf(-gk[1]));
            float so = 1.f / (1.f + __expf(-gk[3]));
            float eg = __expf(2.f * gk[2]); float tg = (eg - 1.f) / (eg + 1.f);
            float c = sf * c_reg + si * tg;
            float ec = __expf(2.f * c); float tc = (ec - 1.f) / (ec + 1.f);
            float hv = so * tc;
            c_reg = c;
            int lenb = sh_len[b];
            int tsb = dd ? (t < lenb ? lenb - 1 - t : t) : t;
            if (t < lenb)
                out[((size_t)tsb * B + b) * 512 + dd * 256 + 8 * jb + ci] = hv;
            float ho = __shfl_xor(hv, 1, 64);
            if (!(ci & 1))
                a_st32(exch_h + (size_t)((p ^ 1) * 64 + dd * 32 + b) * 128 + 4 * jb + (ci >> 1),
                       packh2(hv, ho));
        }
        asm volatile("s_waitcnt vmcnt(0)" ::: "memory");
        __syncthreads();
        if (tid == 0) a_st32(fl_h + jb * 4, (u32)(t + 2));
    }
}

extern "C" void kernel_launch(void* const* d_in, const int* in_sizes, int n_in,
                              void* d_out, int out_size, void* d_ws, size_t ws_size,
                              hipStream_t stream) {
    const float* cv    = (const float*)d_in[0];
    const int*   cmask = (const int*)  d_in[1];
    const float* qv    = (const float*)d_in[2];
    const int*   qmask = (const int*)  d_in[3];
    const float* Wq    = (const float*)d_in[4];
    const float* bq    = (const float*)d_in[5];
    const float* Wp    = (const float*)d_in[6];
    const float* bp    = (const float*)d_in[7];
    const float* Wr    = (const float*)d_in[8];
    const float* br    = (const float*)d_in[9];
    const float* Wg    = (const float*)d_in[10];
    const float* bg    = (const float*)d_in[11];
    const float* ln_g  = (const float*)d_in[12];
    const float* ln_b  = (const float*)d_in[13];
    const float* Wih   = (const float*)d_in[14];
    const float* Whh   = (const float*)d_in[15];
    const float* b_ih  = (const float*)d_in[16];
    const float* b_hh  = (const float*)d_in[17];
    float* out = (float*)d_out;

    uint8_t* ws = (uint8_t*)d_ws;
    u32*    Wcp = (u32*)ws;      ws += (size_t)2 * 1024 * 384 * 4;     // 3.0 MB
    u32*    Wrp = (u32*)ws;      ws += (size_t)2 * 256 * 128 * 4;      // 256 KB
    __half* whp = (__half*)ws;   ws += (size_t)2 * 32 * 50 * 256 * 2;  // 1.6 MB
    __half* hpp = (__half*)ws;   ws += (size_t)2 * 32 * 300 * 256 * 2; // 9.8 MB
    u32*   exch_h  = (u32*)ws;   ws += (size_t)2 * 64 * 128 * 4;       // 64 KB
    u32*   exch_hr = (u32*)ws;   ws += (size_t)64 * 256 * 4;           // 64 KB
    u32*   exch_z  = (u32*)ws;   ws += (size_t)64 * 256 * 4;           // 64 KB
    u32*   flags   = (u32*)ws;                                         // 3 KB

    hipMemsetAsync(flags, 0, (size_t)3 * 2 * 128 * 4, stream);
    hipLaunchKernelGGL(pack_wc_rows, dim3(3072), dim3(256), 0, stream, Wih, Whh, Wcp);
    hipLaunchKernelGGL(pack_wr_rows, dim3(256), dim3(256), 0, stream, Wr, Wrp);
    hipLaunchKernelGGL(prep_proj, dim3(2 * 32 * 7), dim3(256), 0, stream,
                       qv, Wq, bq, whp, QL, 7);
    hipLaunchKernelGGL(prep_proj, dim3(2 * 32 * 38), dim3(256), 0, stream,
                       cv, Wp, bp, hpp, PL, 38);
    hipLaunchKernelGGL(scan4, dim3(64), dim3(256), 0, stream,
                       cv, cmask, qv, qmask, Wg, bg, ln_g, ln_b, br, b_ih, b_hh,
                       Wcp, Wrp, whp, hpp, exch_h, exch_hr, exch_z, flags, out);
}